// Round 5
// baseline (24.250 us; speedup 1.0000x reference)
//
#include <hip/hip_runtime.h>
#include <math.h>

#define NPTS 2048
#define IMG_W 512
#define IMG_H 512
#define TILE 16
#define TILES_X (IMG_W / TILE)
#define TILES_Y (IMG_H / TILE)
#define NTILES (TILES_X * TILES_Y)
#define RSTRIDE 12   // w0=(ux,uy,A,B) w1=(C,a,depth,th) w2=(r,g,b,0)
#define MAXPER 256   // per-tile list capacity (expected max ~70)

// ws layout (floats/ints):
//   records: [0, 2048*12)                         = 98304 B
//   counts:  ints at byte 98304, 1024 ints        = 4096 B
//   lists:   ints at byte 102400, 1024*256 ints   = 1 MB
#define WS_COUNTS_BYTE 98304
#define WS_LISTS_BYTE 102400

// ---------------------------------------------------------------------------
// Kernel A: fused setup + global stable rank-sort + tile binning.
// 256 blocks x 256 threads, 32 threads per point (8 points per block).
// Each block recomputes all 2048 depths into LDS; each 32-lane group ranks
// its point, writes the packed record at slot `rank`, then bins the point
// into every tile whose corner-bound test passes (one tile per sub-lane).
// ---------------------------------------------------------------------------
__global__ __launch_bounds__(256) void gs_sortbin(
    const float* __restrict__ pc,   // (N,3)
    const float* __restrict__ col,  // (N,3)
    const float* __restrict__ alp,  // (N,)
    const float* __restrict__ con,  // (N,3)
    const float* __restrict__ q,    // (4,)
    const float* __restrict__ t,    // (3,)
    const float* __restrict__ K,    // (3,3)
    float* __restrict__ records,
    int* __restrict__ counts,
    int* __restrict__ lists) {
  __shared__ float sd[NPTS];
  int tid = threadIdx.x;

  float qx = q[0], qy = q[1], qz = q[2], qw = q[3];
  float r00 = 1.f - 2.f * (qy * qy + qz * qz), r01 = 2.f * (qx * qy - qz * qw),
        r02 = 2.f * (qx * qz + qy * qw);
  float r10 = 2.f * (qx * qy + qz * qw), r11 = 1.f - 2.f * (qx * qx + qz * qz),
        r12 = 2.f * (qy * qz - qx * qw);
  float r20 = 2.f * (qx * qz - qy * qw), r21 = 2.f * (qy * qz + qx * qw),
        r22 = 1.f - 2.f * (qx * qx + qy * qy);
  float t0 = t[0], t1 = t[1], t2 = t[2];
  float fx = K[0], cx = K[2], fy = K[4], cy = K[5];

  for (int j = tid; j < NPTS; j += 256) {
    float x = pc[3 * j], y = pc[3 * j + 1], z = pc[3 * j + 2];
    sd[j] = r20 * x + r21 * y + r22 * z + t2;
  }
  __syncthreads();

  int g = blockIdx.x * 8 + (tid >> 5);  // point index
  int sub = tid & 31;
  float di = sd[g];
  int rank = 0;
  const float4* sd4 = (const float4*)sd;
#pragma unroll
  for (int jj = 0; jj < NPTS / (32 * 4); jj++) {
    int j4 = jj * 32 + sub;
    float4 dv = sd4[j4];
    int jb = j4 * 4;
    rank += (dv.x < di) || (dv.x == di && jb + 0 < g);
    rank += (dv.y < di) || (dv.y == di && jb + 1 < g);
    rank += (dv.z < di) || (dv.z == di && jb + 2 < g);
    rank += (dv.w < di) || (dv.w == di && jb + 3 < g);
  }
  rank += __shfl_xor(rank, 1);
  rank += __shfl_xor(rank, 2);
  rank += __shfl_xor(rank, 4);
  rank += __shfl_xor(rank, 8);
  rank += __shfl_xor(rank, 16);  // all 32 sub-lanes hold the full rank

  // all lanes of the group recompute the projection (uniform loads, cheap)
  float x = pc[3 * g], y = pc[3 * g + 1], z = pc[3 * g + 2];
  float X = r00 * x + r01 * y + r02 * z + t0;
  float Y = r10 * x + r11 * y + r12 * z + t1;
  float Z = di;
  float inv = 1.0f / (Z + 1e-6f);
  float ux = (fx * X + cx * Z) * inv;
  float uy = (fy * Y + cy * Z) * inv;
  float A = con[3 * g], B = con[3 * g + 1], C = con[3 * g + 2];
  float a = alp[g];
  float th = 2.0f * __logf(255.0f * a);

  if (sub == 0) {
    float4* d = (float4*)(records + (size_t)rank * RSTRIDE);
    d[0] = {ux, uy, A, B};
    d[1] = {C, a, Z, th};
    d[2] = {col[3 * g], col[3 * g + 1], col[3 * g + 2], 0.0f};
  }

  // ---- binning: bbox tile range, then exact corner-bound test per tile ----
  float ths = th + 1e-3f;  // same slack as the per-tile cull
  float lamx = fmaxf(A - fabsf(B), 0.0f), lamy = fmaxf(C - fabsf(B), 0.0f);
  if (ths >= 0.0f) {
    float rx = (lamx > 1e-6f) ? __fsqrt_rn(ths / lamx) : 1e9f;
    float ry = (lamy > 1e-6f) ? __fsqrt_rn(ths / lamy) : 1e9f;
    int x0 = (int)ceilf((ux - rx - 15.5f) * (1.0f / 16.0f));
    int x1 = (int)floorf((ux + rx - 0.5f) * (1.0f / 16.0f));
    int y0 = (int)ceilf((uy - ry - 15.5f) * (1.0f / 16.0f));
    int y1 = (int)floorf((uy + ry - 0.5f) * (1.0f / 16.0f));
    x0 = max(x0, 0); x1 = min(x1, TILES_X - 1);
    y0 = max(y0, 0); y1 = min(y1, TILES_Y - 1);
    int nx = x1 - x0 + 1, ny = y1 - y0 + 1;
    int nt = (nx > 0 && ny > 0) ? nx * ny : 0;
    for (int s = sub; s < nt; s += 32) {
      int ty = y0 + s / nx, tx = x0 + s % nx;
      float tpx0 = tx * 16 + 0.5f, tpx1 = tx * 16 + 15.5f;
      float tpy0 = ty * 16 + 0.5f, tpy1 = ty * 16 + 15.5f;
      float dxm = fmaxf(0.0f, fmaxf(tpx0 - ux, ux - tpx1));
      float dym = fmaxf(0.0f, fmaxf(tpy0 - uy, uy - tpy1));
      float bound = lamx * dxm * dxm + lamy * dym * dym;
      if (bound <= ths) {
        int tl = ty * TILES_X + tx;
        int slot = atomicAdd(&counts[tl], 1);
        if (slot < MAXPER) lists[tl * MAXPER + slot] = rank;
      }
    }
  }
}

// ---------------------------------------------------------------------------
// Kernel B: rasterizer. One 256-thread block per 16x16 tile. Reads its own
// tile list (~40 ranks), counting-sorts the ranks (rank order == reference
// stable depth order), gathers records to LDS, composites front-to-back.
// ---------------------------------------------------------------------------
__global__ __launch_bounds__(256) void gs_raster(
    const float* __restrict__ records,
    const int* __restrict__ counts,
    const int* __restrict__ lists,
    float* __restrict__ out) {
  __shared__ float s_pts[MAXPER * RSTRIDE];
  __shared__ int s_rank[MAXPER];
  __shared__ int s_order[MAXPER];

  int tid = threadIdx.x;
  int tile = blockIdx.x;
  int tilex = (tile % TILES_X) * TILE;
  int tiley = (tile / TILES_X) * TILE;
  int lx = tid % TILE, ly = tid / TILE;
  float px = tilex + lx + 0.5f, py = tiley + ly + 0.5f;

  int k = counts[tile];

  float T = 1.0f, accr = 0.f, accg = 0.f, accb = 0.f, accd = 0.f;

#define COMPOSITE(w0, w1, w2)                                              \
  {                                                                        \
    float dx = px - w0.x, dy = py - w0.y;                                  \
    float pw =                                                             \
        -0.5f * (w0.z * dx * dx + 2.0f * w0.w * dx * dy + w1.x * dy * dy); \
    float gg = __expf(fminf(pw, 0.0f));                                    \
    float prod = gg * w1.y;                                                \
    if (prod >= (1.0f / 255.0f)) {                                         \
      float al = fminf(prod, 0.99f);                                       \
      float w = T * al;                                                    \
      accr += w * w2.x;                                                    \
      accg += w * w2.y;                                                    \
      accb += w * w2.z;                                                    \
      accd += w * w1.z;                                                    \
      T *= (1.0f - al);                                                    \
    }                                                                      \
  }

  if (k <= MAXPER) {
    int myrank = (tid < k) ? lists[tile * MAXPER + tid] : 0x7fffffff;
    s_rank[tid] = myrank;
    __syncthreads();
    if (tid < k) {
      int pos = 0;
      for (int j = 0; j < k; j++) pos += (s_rank[j] < myrank);
      s_order[pos] = myrank;
    }
    __syncthreads();
    // cooperative gather of the k records (3 float4 each) into LDS
    for (int idx = tid; idx < k * 3; idx += 256) {
      int e = idx / 3, p = idx - e * 3;
      int rec = s_order[e];
      float4 v = ((const float4*)(records + (size_t)rec * RSTRIDE))[p];
      ((float4*)(s_pts + (size_t)e * RSTRIDE))[p] = v;
    }
    __syncthreads();
    for (int kk = 0; kk < k; kk++) {
      const float4* p4 = (const float4*)(s_pts + (size_t)kk * RSTRIDE);
      float4 w0 = p4[0], w1 = p4[1], w2 = p4[2];
      COMPOSITE(w0, w1, w2);
      if (T < 1e-4f) break;
    }
  } else {
    // exact fallback (never expected): walk all records in rank order,
    // applying the same tile corner-bound cull.
    float tpx0 = tilex + 0.5f, tpx1 = tilex + TILE - 0.5f;
    float tpy0 = tiley + 0.5f, tpy1 = tiley + TILE - 0.5f;
    for (int r = 0; r < NPTS; r++) {
      const float4* p4 = (const float4*)(records + (size_t)r * RSTRIDE);
      float4 w0 = p4[0], w1 = p4[1];
      float lamx = fmaxf(w0.z - fabsf(w0.w), 0.0f);
      float lamy = fmaxf(w1.x - fabsf(w0.w), 0.0f);
      float dxm = fmaxf(0.0f, fmaxf(tpx0 - w0.x, w0.x - tpx1));
      float dym = fmaxf(0.0f, fmaxf(tpy0 - w0.y, w0.y - tpy1));
      float bound = lamx * dxm * dxm + lamy * dym * dym;
      if (bound <= w1.w + 1e-3f) {
        float4 w2 = p4[2];
        COMPOSITE(w0, w1, w2);
        if (T < 1e-4f) break;
      }
    }
  }
#undef COMPOSITE

  int o = ((tiley + ly) * IMG_W + (tilex + lx)) * 5;
  out[o + 0] = accr;
  out[o + 1] = accg;
  out[o + 2] = accb;
  out[o + 3] = accd;
  out[o + 4] = 1.0f - T;
}

extern "C" void kernel_launch(void* const* d_in, const int* in_sizes, int n_in,
                              void* d_out, int out_size, void* d_ws,
                              size_t ws_size, hipStream_t stream) {
  const float* pc = (const float*)d_in[0];
  const float* col = (const float*)d_in[1];
  const float* alp = (const float*)d_in[2];
  const float* con = (const float*)d_in[3];
  const float* q = (const float*)d_in[4];
  const float* t = (const float*)d_in[5];
  const float* K = (const float*)d_in[6];
  float* out = (float*)d_out;

  float* records = (float*)d_ws;
  int* counts = (int*)((char*)d_ws + WS_COUNTS_BYTE);
  int* lists = (int*)((char*)d_ws + WS_LISTS_BYTE);

  hipMemsetAsync(counts, 0, NTILES * sizeof(int), stream);
  gs_sortbin<<<NPTS / 8, 256, 0, stream>>>(pc, col, alp, con, q, t, K,
                                           records, counts, lists);
  gs_raster<<<NTILES, 256, 0, stream>>>(records, counts, lists, out);
}

// Round 6
// 18.384 us; speedup vs baseline: 1.3191x; 1.3191x over previous
//
#include <hip/hip_runtime.h>
#include <math.h>

#define NPTS 2048
#define IMG_W 512
#define IMG_H 512
#define RW 32              // region width (px)
#define RH 16              // region height (px)
#define NBX (IMG_W / RW)   // 16
#define NBY (IMG_H / RH)   // 32
#define NTHREADS (RW * RH) // 512
#define NCHUNK (NPTS / NTHREADS)  // 4
#define CAP 512            // survivor capacity (expected worst ~90)
#define RSTRIDE 12         // w0=(ux,uy,A,B) w1=(C,a,depth,th) w2=(r,g,b,0)

// ---------------------------------------------------------------------------
// Single fused kernel: one 512-thread block per 32x16 pixel region.
// 1) cull all 2048 points vs region (projection on the fly, 4 pts/thread)
// 2) ordered compaction of survivor records into LDS + u64 (depth,orig) keys
// 3) rank via u64 key compare -> s_order (reference stable argsort order
//    restricted to contributing points; culled points have alpha==0 exactly)
// 4) front-to-back composite, no early-exit break (enables pipelining)
// ---------------------------------------------------------------------------
__global__ __launch_bounds__(NTHREADS) void gs_fused(
    const float* __restrict__ pc,   // (N,3)
    const float* __restrict__ col,  // (N,3)
    const float* __restrict__ alp,  // (N,)
    const float* __restrict__ con,  // (N,3)
    const float* __restrict__ q,    // (4,)
    const float* __restrict__ t,    // (3,)
    const float* __restrict__ K,    // (3,3)
    float* __restrict__ out) {
  __shared__ float s_pts[CAP * RSTRIDE];
  __shared__ unsigned long long s_key[CAP];
  __shared__ int s_order[CAP];
  __shared__ int s_cnt[NCHUNK * 8];  // [chunk][wave]

  int tid = threadIdx.x;
  int lane = tid & 63, wave = tid >> 6;
  int rx = (blockIdx.x % NBX) * RW;
  int ry = (blockIdx.x / NBX) * RH;
  int lx = tid % RW, ly = tid / RW;
  float px = rx + lx + 0.5f, py = ry + ly + 0.5f;
  float tx0 = rx + 0.5f, tx1 = rx + RW - 0.5f;
  float ty0 = ry + 0.5f, ty1 = ry + RH - 0.5f;

  // wave-uniform camera params
  float qx = q[0], qy = q[1], qz = q[2], qw = q[3];
  float r00 = 1.f - 2.f * (qy * qy + qz * qz), r01 = 2.f * (qx * qy - qz * qw),
        r02 = 2.f * (qx * qz + qy * qw);
  float r10 = 2.f * (qx * qy + qz * qw), r11 = 1.f - 2.f * (qx * qx + qz * qz),
        r12 = 2.f * (qy * qz - qx * qw);
  float r20 = 2.f * (qx * qz - qy * qw), r21 = 2.f * (qy * qz + qx * qw),
        r22 = 1.f - 2.f * (qx * qx + qy * qy);
  float t0 = t[0], t1 = t[1], t2 = t[2];
  float fx = K[0], cx = K[2], fy = K[4], cy = K[5];

#define PROJ(i, ux, uy, Z)                      \
  float ux, uy, Z;                              \
  {                                             \
    float x = pc[3 * (i)], y = pc[3 * (i) + 1], \
          z = pc[3 * (i) + 2];                  \
    Z = r20 * x + r21 * y + r22 * z + t2;       \
    float X = r00 * x + r01 * y + r02 * z + t0; \
    float Y = r10 * x + r11 * y + r12 * z + t1; \
    float inv = 1.0f / (Z + 1e-6f);             \
    ux = (fx * X + cx * Z) * inv;               \
    uy = (fy * Y + cy * Z) * inv;               \
  }

  // ---- phase 1: cull ----
  unsigned pmask = 0;
  int miw[NCHUNK];
#pragma unroll
  for (int c = 0; c < NCHUNK; c++) {
    int i = c * NTHREADS + tid;
    PROJ(i, ux, uy, Z);
    float A = con[3 * i], B = con[3 * i + 1], C = con[3 * i + 2];
    float a = alp[i];
    float th = 2.0f * __logf(255.0f * a);
    float absB = fabsf(B);
    float dxm = fmaxf(0.0f, fmaxf(tx0 - ux, ux - tx1));
    float dym = fmaxf(0.0f, fmaxf(ty0 - uy, uy - ty1));
    float bound =
        fmaxf(A - absB, 0.0f) * dxm * dxm + fmaxf(C - absB, 0.0f) * dym * dym;
    bool pred = bound <= th + 1e-3f;
    unsigned long long m = __ballot(pred);
    miw[c] = __popcll(m & ((1ull << lane) - 1ull));
    if (lane == 0) s_cnt[c * 8 + wave] = (int)__popcll(m);
    pmask |= (unsigned)pred << c;
  }
  __syncthreads();

  // ---- prefix sums (broadcast LDS reads) ----
  int start[NCHUNK], total;
  {
    int run = 0;
#pragma unroll
    for (int c = 0; c < NCHUNK; c++) {
      int woff = 0, ct = 0;
#pragma unroll
      for (int w = 0; w < 8; w++) {
        int v = s_cnt[c * 8 + w];
        woff += (w < wave) ? v : 0;
        ct += v;
      }
      start[c] = run + woff;
      run += ct;
    }
    total = run;
  }

  float T = 1.0f, accr = 0.f, accg = 0.f, accb = 0.f, accd = 0.f;

#define COMPOSITE(w0, w1, w2)                                              \
  {                                                                        \
    float dx = px - w0.x, dy = py - w0.y;                                  \
    float pw =                                                             \
        -0.5f * (w0.z * dx * dx + 2.0f * w0.w * dx * dy + w1.x * dy * dy); \
    float gg = __expf(fminf(pw, 0.0f));                                    \
    float prod = gg * w1.y;                                                \
    if (prod >= (1.0f / 255.0f)) {                                         \
      float al = fminf(prod, 0.99f);                                       \
      float w = T * al;                                                    \
      accr += w * w2.x;                                                    \
      accg += w * w2.y;                                                    \
      accb += w * w2.z;                                                    \
      accd += w * w1.z;                                                    \
      T *= (1.0f - al);                                                    \
    }                                                                      \
  }

  if (total <= CAP) {
    // ---- phase 2: compact survivors ----
#pragma unroll
    for (int c = 0; c < NCHUNK; c++) {
      if ((pmask >> c) & 1) {
        int i = c * NTHREADS + tid;
        PROJ(i, ux, uy, Z);
        float a = alp[i];
        float th = 2.0f * __logf(255.0f * a);
        int slot = start[c] + miw[c];
        float4* d = (float4*)(s_pts + (size_t)slot * RSTRIDE);
        d[0] = {ux, uy, con[3 * i], con[3 * i + 1]};
        d[1] = {con[3 * i + 2], a, Z, th};
        d[2] = {col[3 * i], col[3 * i + 1], col[3 * i + 2], 0.0f};
        // depth > 0 always, so float bits are order-preserving as uint
        s_key[slot] =
            ((unsigned long long)__float_as_uint(Z) << 32) | (unsigned)i;
      }
    }
    __syncthreads();

    // ---- phase 3: rank survivors by (depth, orig) ----
    if (tid < total) {
      unsigned long long myk = s_key[tid];
      int pos = 0;
      for (int j = 0; j < total; j++) pos += (s_key[j] < myk);
      s_order[pos] = tid;
    }
    __syncthreads();

    // ---- phase 4: composite front-to-back (no break -> pipelined) ----
    for (int kk = 0; kk < total; kk++) {
      int e = s_order[kk];
      const float4* p4 = (const float4*)(s_pts + (size_t)e * RSTRIDE);
      float4 w0 = p4[0], w1 = p4[1], w2 = p4[2];
      COMPOSITE(w0, w1, w2);
    }
  } else {
    // ---- exact fallback (never expected): block-wide select-min merge ----
    float dep[NCHUNK];
#pragma unroll
    for (int c = 0; c < NCHUNK; c++) {
      int i = c * NTHREADS + tid;
      float x = pc[3 * i], y = pc[3 * i + 1], z = pc[3 * i + 2];
      dep[c] = r20 * x + r21 * y + r22 * z + t2;
    }
    unsigned live = pmask;
    float* s_rd = s_pts;                    // 512 floats
    int* s_ro = (int*)(s_pts + NTHREADS);   // 512 ints
    float* s_rec = s_pts + 2 * NTHREADS;    // 12-float winner record
    while (1) {
      float bd = 1e30f;
      int bo = 0x7fffffff;
#pragma unroll
      for (int c = 0; c < NCHUNK; c++) {
        if ((live >> c) & 1) {
          int o = c * NTHREADS + tid;
          if (dep[c] < bd || (dep[c] == bd && o < bo)) { bd = dep[c]; bo = o; }
        }
      }
      s_rd[tid] = bd;
      s_ro[tid] = bo;
      __syncthreads();
      float wd = 1e30f;
      int wo = 0x7fffffff;
      for (int j = 0; j < NTHREADS; j++) {
        float d = s_rd[j];
        int o = s_ro[j];
        if (d < wd || (d == wd && o < wo)) { wd = d; wo = o; }
      }
      __syncthreads();
      if (wo == 0x7fffffff) break;
      if (tid == (wo & (NTHREADS - 1))) {
        int i = wo;
        PROJ(i, ux, uy, Z);
        float a = alp[i];
        float4* d = (float4*)s_rec;
        d[0] = {ux, uy, con[3 * i], con[3 * i + 1]};
        d[1] = {con[3 * i + 2], a, Z, 0.0f};
        d[2] = {col[3 * i], col[3 * i + 1], col[3 * i + 2], 0.0f};
        live &= ~(1u << (wo / NTHREADS));
      }
      __syncthreads();
      float4 w0 = ((float4*)s_rec)[0], w1 = ((float4*)s_rec)[1],
             w2 = ((float4*)s_rec)[2];
      COMPOSITE(w0, w1, w2);
    }
  }
#undef COMPOSITE
#undef PROJ

  int o = ((ry + ly) * IMG_W + (rx + lx)) * 5;
  out[o + 0] = accr;
  out[o + 1] = accg;
  out[o + 2] = accb;
  out[o + 3] = accd;
  out[o + 4] = 1.0f - T;
}

extern "C" void kernel_launch(void* const* d_in, const int* in_sizes, int n_in,
                              void* d_out, int out_size, void* d_ws,
                              size_t ws_size, hipStream_t stream) {
  const float* pc = (const float*)d_in[0];
  const float* col = (const float*)d_in[1];
  const float* alp = (const float*)d_in[2];
  const float* con = (const float*)d_in[3];
  const float* q = (const float*)d_in[4];
  const float* t = (const float*)d_in[5];
  const float* K = (const float*)d_in[6];
  float* out = (float*)d_out;

  gs_fused<<<NBX * NBY, NTHREADS, 0, stream>>>(pc, col, alp, con, q, t, K,
                                               out);
}